// Round 7
// baseline (368.115 us; speedup 1.0000x reference)
//
#include <hip/hip_runtime.h>
#include <hip/hip_bf16.h>

#define NTOK   65536
#define KCODES 1024
#define DIM    256
#define LOSS_OFF ((size_t)NTOK * DIM)
#define IDX_OFF  (LOSS_OFF + 1)

#define MARGA 3.5e-4f     // a-space margin (validated rounds 5/6)

// ---- scratch layout inside the z_q output region (float-slot offsets) ----
// all consumed before vq_gather overwrites z_q rows.
#define SC_ZSQ    0              // 65536 f
#define SC_A1     65536          // 65536 f
#define SC_LOSS2  131072         // 65536 f
#define SC_ESQ    196608         // 1024 f
#define SC_ESQNH  197632         // 1024 f
#define SC_PART   198656         // 64 f
#define SC_WCNT   198720         // 1 int
#define SC_WCNT2  198721         // 1 int
#define SC_CNTG   198784         // 65536 int
#define SC_LISTS  264320         // 262144 int
#define SC_WLIST  526464         // 65536 int
#define SC_WLIST2 592000         // 4096 int
#define SC_EHIMG  596096         // 131072 f-slots = 512 KB bf16 emb image
#define SC_ZIMG   727168         // 8388608 f-slots = 32 MB bf16 z image (pre-swizzled)

typedef __attribute__((ext_vector_type(8))) short short8;
typedef __attribute__((ext_vector_type(4))) float f32x4;

__device__ __forceinline__ unsigned f2bf(float x) {
    unsigned u = __float_as_uint(x);
    return (u + 0x7FFFu + ((u >> 16) & 1u)) >> 16;   // RNE
}

__device__ __forceinline__ void gload16(const void* g, void* l) {
    __builtin_amdgcn_global_load_lds((const __attribute__((address_space(1))) unsigned int*)g,
                                     (__attribute__((address_space(3))) unsigned int*)l,
                                     16, 0, 0);
}

// faithful fp32 distance (validated rounds 4-6): sequential single-acc FMA chain
__device__ __forceinline__ float faithful_d(const float* __restrict__ z,
                                            const float* __restrict__ emb,
                                            float zsq, float esq, int tok, int c) {
    const float4* zr = (const float4*)(z + (size_t)tok * DIM);
    const float4* er = (const float4*)(emb + (size_t)c * DIM);
    float acc = 0.f;
#pragma unroll 8
    for (int q = 0; q < 64; ++q) {
        float4 a = zr[q], b = er[q];
        acc = fmaf(a.x, b.x, acc); acc = fmaf(a.y, b.y, acc);
        acc = fmaf(a.z, b.z, acc); acc = fmaf(a.w, b.w, acc);
    }
    float t1 = zsq + esq;
    return t1 - 2.0f * acc;
}

// wave-parallel numpy pairwise sum-of-squares replica (16 lanes per 256-row)
__device__ __forceinline__ float np_rowsq256_wave(const float* row, int sub) {
    const int j = sub & 7, half = sub >> 3;
    const float* a = row + half * 128 + j;
    float r = 0.f;
#pragma unroll
    for (int i = 0; i < 16; ++i) {
        float v = a[i * 8];
        float sq = v * v;
        asm volatile("" : "+v"(sq));
        r += sq;
    }
    float t = r + __shfl_xor(r, 1, 64);
    t = t + __shfl_xor(t, 2, 64);
    t = t + __shfl_xor(t, 4, 64);
    t = t + __shfl_xor(t, 8, 64);
    return t;
}

// ---------------- prep: esq / esqnh (+ worklist counters reset) ----------------
__global__ __launch_bounds__(256) void vq_prep_esq(const float* __restrict__ emb,
                                                   float* __restrict__ esq,
                                                   float* __restrict__ esqnh,
                                                   int* __restrict__ wcnt,
                                                   int* __restrict__ wcnt2) {
    if (blockIdx.x == 0 && threadIdx.x == 0) { *wcnt = 0; *wcnt2 = 0; }
    int code = blockIdx.x * 16 + (threadIdx.x >> 4);   // grid 64
    int sub = threadIdx.x & 15;
    float tot = np_rowsq256_wave(emb + (size_t)code * DIM, sub);
    if (sub == 0) { esq[code] = tot; esqnh[code] = -0.5f * tot; }
}

// ---------------- prep: zsq (np-faithful) + pre-swizzled bf16 z image ----------------
__global__ __launch_bounds__(256) void vq_prep_z(const float* __restrict__ z,
                                                 float* __restrict__ zsq,
                                                 unsigned short* __restrict__ zimg) {
    int tok = blockIdx.x * 16 + (threadIdx.x >> 4);    // grid 4096
    int sub = threadIdx.x & 15;
    float tot = np_rowsq256_wave(z + (size_t)tok * DIM, sub);
    if (sub == 0) zsq[tok] = tot;

    // image: 2×16B granules per lane; row L1-hot from zsq phase
    const float* src = z + (size_t)tok * DIM + sub * 16;
    float4 v0 = *(const float4*)&src[0],  v1 = *(const float4*)&src[4];
    float4 v2 = *(const float4*)&src[8],  v3 = *(const float4*)&src[12];
    uint4 p0, p1;
    p0.x = f2bf(v0.x) | (f2bf(v0.y) << 16);  p0.y = f2bf(v0.z) | (f2bf(v0.w) << 16);
    p0.z = f2bf(v1.x) | (f2bf(v1.y) << 16);  p0.w = f2bf(v1.z) | (f2bf(v1.w) << 16);
    p1.x = f2bf(v2.x) | (f2bf(v2.y) << 16);  p1.y = f2bf(v2.z) | (f2bf(v2.w) << 16);
    p1.z = f2bf(v3.x) | (f2bf(v3.y) << 16);  p1.w = f2bf(v3.z) | (f2bf(v3.w) << 16);
    int bid = tok >> 6, tl = tok & 63;
    char* base = (char*)zimg + (size_t)bid * 32768 + tl * 512;
    int g0 = sub * 2, g1 = sub * 2 + 1;
    *(uint4*)(base + ((g0 * 16) ^ ((tl & 7) << 4))) = p0;
    *(uint4*)(base + ((g1 * 16) ^ ((tl & 7) << 4))) = p1;
}

// ---------------- prep: bf16 emb image in pre-swizzled LDS slice layout ----------------
__global__ __launch_bounds__(256) void vq_prep_eimg(const float* __restrict__ emb,
                                                    unsigned short* __restrict__ img) {
    int job = blockIdx.x * 256 + threadIdx.x;   // grid 32
    int code = job >> 3, ks = job & 7;
    int cc = (code >> 6) & 3, lcl = (code >> 8) * 64 + (code & 63);
    const float* src = emb + (size_t)code * DIM + ks * 32;
    char* base = (char*)img + (size_t)(cc * 8 + ks) * 16384;
#pragma unroll
    for (int q = 0; q < 4; ++q) {
        float4 v0 = *(const float4*)&src[q * 8];
        float4 v1 = *(const float4*)&src[q * 8 + 4];
        uint4 p;
        p.x = f2bf(v0.x) | (f2bf(v0.y) << 16);
        p.y = f2bf(v0.z) | (f2bf(v0.w) << 16);
        p.z = f2bf(v1.x) | (f2bf(v1.y) << 16);
        p.w = f2bf(v1.z) | (f2bf(v1.w) << 16);
        *(uint4*)(base + lcl * 64 + ((q * 16) ^ (((lcl >> 1) & 3) << 4))) = p;
    }
}

// ---------------- GEMM filter: PASS1 = per-token max(a); PASS2 = enumerate+finalize ----------------
template<int PASS>
__global__ __launch_bounds__(256, 2) void vq_gemm(const unsigned short* __restrict__ zimg,
                                                  const unsigned short* __restrict__ img,
                                                  const float* __restrict__ esqnh,
                                                  const float* __restrict__ zsq,
                                                  float* __restrict__ a1,
                                                  int* __restrict__ wcnt,
                                                  int* __restrict__ wlist,
                                                  int* __restrict__ cntg,
                                                  int* __restrict__ listsg,
                                                  float* __restrict__ loss2,
                                                  float* __restrict__ dout) {
    __shared__ __align__(16) short zh_s[64 * 256];    // 32 KB (async-staged z image)
    __shared__ __align__(16) short eh_s[2][8192];     // 2 x 16 KB (async-staged e image)
    __shared__ float a1w_s[4][64];
    __shared__ int cnt_s[64];
    __shared__ int lists_s[256];

    const int tid = threadIdx.x, bid = blockIdx.x;
    const int w = tid >> 6, l = tid & 63;
    const int t0 = bid * 64;

    // stage zh via async copy (byte-for-byte, already swizzled in image)
    {
        const char* gz = (const char*)zimg + (size_t)bid * 32768 + w * 8192 + l * 16;
        char* lz = (char*)zh_s + w * 8192;
#pragma unroll
        for (int i = 0; i < 8; ++i) gload16(gz + i * 1024, lz + i * 1024);
    }
    if (PASS == 2 && tid < 64) cnt_s[tid] = 0;
    // issue eh slice 0
    {
        const char* gs = (const char*)img + w * 4096 + l * 16;
        char* ld = (char*)&eh_s[0][0] + w * 4096;
#pragma unroll
        for (int i = 0; i < 4; ++i) gload16(gs + i * 1024, ld + i * 1024);
    }
    __syncthreads();

    float thrv[4], amax[4];
#pragma unroll
    for (int tf = 0; tf < 4; ++tf) {
        amax[tf] = -3.4e38f;
        if (PASS == 2) thrv[tf] = a1[t0 + tf * 16 + (l & 15)] - MARGA;
    }

    f32x4 acc[4][4];

    for (int c = 0; c < 4; ++c) {
#pragma unroll
        for (int f = 0; f < 4; ++f) {
            f32x4 e4 = *(const f32x4*)&esqnh[w * 256 + c * 64 + f * 16 + (l >> 4) * 4];
#pragma unroll
            for (int tf = 0; tf < 4; ++tf) acc[f][tf] = e4;
        }
        for (int ks = 0; ks < 8; ++ks) {
            int s = c * 8 + ks, buf = s & 1;
            if (s < 31) {
                const char* gs = (const char*)img + (size_t)(s + 1) * 16384 + w * 4096 + l * 16;
                char* ld = (char*)&eh_s[buf ^ 1][0] + w * 4096;
#pragma unroll
                for (int i = 0; i < 4; ++i) gload16(gs + i * 1024, ld + i * 1024);
            }
            short8 bfr[4], afr[4];
#pragma unroll
            for (int tf = 0; tf < 4; ++tf) {
                int tokl = tf * 16 + (l & 15);
                int byte = tokl * 512 + ((ks * 64 + (l >> 4) * 16) ^ ((tokl & 7) << 4));
                bfr[tf] = *(short8*)((char*)zh_s + byte);
            }
#pragma unroll
            for (int f = 0; f < 4; ++f) {
                int lcl = w * 64 + f * 16 + (l & 15);
                int byte = lcl * 64 + (((l >> 4) * 16) ^ (((lcl >> 1) & 3) << 4));
                afr[f] = *(short8*)((char*)&eh_s[buf][0] + byte);
            }
#pragma unroll
            for (int f = 0; f < 4; ++f)
#pragma unroll
                for (int tf = 0; tf < 4; ++tf)
                    acc[f][tf] = __builtin_amdgcn_mfma_f32_16x16x32_bf16(
                        afr[f], bfr[tf], acc[f][tf], 0, 0, 0);
            __syncthreads();
        }
        if (PASS == 1) {
#pragma unroll
            for (int tf = 0; tf < 4; ++tf) {
                float m0 = fmaxf(fmaxf(acc[0][tf][0], acc[0][tf][1]), fmaxf(acc[0][tf][2], acc[0][tf][3]));
                float m1 = fmaxf(fmaxf(acc[1][tf][0], acc[1][tf][1]), fmaxf(acc[1][tf][2], acc[1][tf][3]));
                float m2 = fmaxf(fmaxf(acc[2][tf][0], acc[2][tf][1]), fmaxf(acc[2][tf][2], acc[2][tf][3]));
                float m3 = fmaxf(fmaxf(acc[3][tf][0], acc[3][tf][1]), fmaxf(acc[3][tf][2], acc[3][tf][3]));
                amax[tf] = fmaxf(amax[tf], fmaxf(fmaxf(m0, m1), fmaxf(m2, m3)));
            }
        } else {
#pragma unroll
            for (int tf = 0; tf < 4; ++tf) {
                int tokl = tf * 16 + (l & 15);
#pragma unroll
                for (int f = 0; f < 4; ++f)
#pragma unroll
                    for (int r = 0; r < 4; ++r) {
                        float a = acc[f][tf][r];
                        if (a >= thrv[tf]) {
                            int code = w * 256 + c * 64 + f * 16 + (l >> 4) * 4 + r;
                            int pos = atomicAdd(&cnt_s[tokl], 1);
                            if (pos < 4) lists_s[tokl * 4 + pos] = code;
                        }
                    }
            }
        }
    }

    if (PASS == 1) {
#pragma unroll
        for (int tf = 0; tf < 4; ++tf) {
            float m = amax[tf];
            m = fmaxf(m, __shfl_xor(m, 16, 64));
            m = fmaxf(m, __shfl_xor(m, 32, 64));
            if (l < 16) a1w_s[w][tf * 16 + l] = m;
        }
        __syncthreads();
        if (tid < 64)
            a1[t0 + tid] = fmaxf(fmaxf(a1w_s[0][tid], a1w_s[1][tid]),
                                 fmaxf(a1w_s[2][tid], a1w_s[3][tid]));
    } else {
        __syncthreads();
        if (tid < 64) {
            int t = t0 + tid, ct = cnt_s[tid];
            if (ct == 1) {
                dout[IDX_OFF + t] = (float)lists_s[tid * 4];
                loss2[t] = fmaf(-2.f, a1[t], zsq[t]);
            } else {
                int pos = atomicAdd(wcnt, 1);
                wlist[pos] = t;
                cntg[t] = ct;
                int m = ct < 4 ? ct : 4;
                for (int i = 0; i < m; ++i) listsg[t * 4 + i] = lists_s[tid * 4 + i];
            }
        }
    }
}

// ---------------- decide (hard): thread per token, 4 interleaved faithful chains ----------------
__global__ __launch_bounds__(256) void vq_decide_hard(const float* __restrict__ z,
                                                      const float* __restrict__ emb,
                                                      const float* __restrict__ zsq,
                                                      const float* __restrict__ esq,
                                                      const int* __restrict__ wcnt,
                                                      const int* __restrict__ wlist,
                                                      const int* __restrict__ cntg,
                                                      const int* __restrict__ listsg,
                                                      int* __restrict__ wcnt2,
                                                      int* __restrict__ wlist2,
                                                      float* __restrict__ loss2,
                                                      float* __restrict__ dout) {
    const int n = wcnt[0];
    for (int q = blockIdx.x * 256 + threadIdx.x; q < n; q += 128 * 256) {
        int tok = wlist[q];
        int ct = cntg[tok];
        if (ct > 4) {
            int p = atomicAdd(wcnt2, 1);
            if (p < 4096) wlist2[p] = tok;
            continue;
        }
        int cand[4];
        cand[0] = listsg[tok * 4];
#pragma unroll
        for (int i = 1; i < 4; ++i) cand[i] = (i < ct) ? listsg[tok * 4 + i] : cand[0];
        float a0 = 0.f, a1v = 0.f, a2 = 0.f, a3 = 0.f;
        const float4* zr = (const float4*)(z + (size_t)tok * DIM);
        const float4* e0 = (const float4*)(emb + (size_t)cand[0] * DIM);
        const float4* e1 = (const float4*)(emb + (size_t)cand[1] * DIM);
        const float4* e2 = (const float4*)(emb + (size_t)cand[2] * DIM);
        const float4* e3 = (const float4*)(emb + (size_t)cand[3] * DIM);
#pragma unroll
        for (int seg = 0; seg < 4; ++seg) {
            float4 zb[16];
#pragma unroll
            for (int qq = 0; qq < 16; ++qq) zb[qq] = zr[seg * 16 + qq];
#pragma unroll
            for (int qq = 0; qq < 16; ++qq) {
                float4 a = zb[qq];
                float4 b0 = e0[seg * 16 + qq], b1 = e1[seg * 16 + qq];
                float4 b2 = e2[seg * 16 + qq], b3 = e3[seg * 16 + qq];
                a0 = fmaf(a.x, b0.x, a0); a0 = fmaf(a.y, b0.y, a0);
                a0 = fmaf(a.z, b0.z, a0); a0 = fmaf(a.w, b0.w, a0);
                a1v = fmaf(a.x, b1.x, a1v); a1v = fmaf(a.y, b1.y, a1v);
                a1v = fmaf(a.z, b1.z, a1v); a1v = fmaf(a.w, b1.w, a1v);
                a2 = fmaf(a.x, b2.x, a2); a2 = fmaf(a.y, b2.y, a2);
                a2 = fmaf(a.z, b2.z, a2); a2 = fmaf(a.w, b2.w, a2);
                a3 = fmaf(a.x, b3.x, a3); a3 = fmaf(a.y, b3.y, a3);
                a3 = fmaf(a.z, b3.z, a3); a3 = fmaf(a.w, b3.w, a3);
            }
        }
        float zq = zsq[tok];
        float d0 = (zq + esq[cand[0]]) - 2.0f * a0;
        float d1 = (zq + esq[cand[1]]) - 2.0f * a1v;
        float d2 = (zq + esq[cand[2]]) - 2.0f * a2;
        float d3 = (zq + esq[cand[3]]) - 2.0f * a3;
        float db = d0; int cb = cand[0];
        if (ct > 1 && (d1 < db || (d1 == db && cand[1] < cb))) { db = d1; cb = cand[1]; }
        if (ct > 2 && (d2 < db || (d2 == db && cand[2] < cb))) { db = d2; cb = cand[2]; }
        if (ct > 3 && (d3 < db || (d3 == db && cand[3] < cb))) { db = d3; cb = cand[3]; }
        dout[IDX_OFF + tok] = (float)cb;
        loss2[tok] = db;
    }
}

// ---------------- decide (scan): wave per token, full 1024 faithful scan (rare) ----------------
__global__ __launch_bounds__(256) void vq_decide_scan(const float* __restrict__ z,
                                                      const float* __restrict__ emb,
                                                      const float* __restrict__ zsq,
                                                      const float* __restrict__ esq,
                                                      const int* __restrict__ wcnt2,
                                                      const int* __restrict__ wlist2,
                                                      float* __restrict__ loss2,
                                                      float* __restrict__ dout) {
    const int w = threadIdx.x >> 6, l = threadIdx.x & 63;
    int n = wcnt2[0];
    if (n > 4096) n = 4096;
    for (int q = blockIdx.x * 4 + w; q < n; q += 64 * 4) {
        const int tok = wlist2[q];
        float best = 3.4e38f; int bidx = 0;
        for (int cs = 0; cs < 16; ++cs) {
            int c = cs * 64 + l;
            float d = faithful_d(z, emb, zsq[tok], esq[c], tok, c);
            if (d < best) { best = d; bidx = c; }
        }
#pragma unroll
        for (int m = 1; m < 64; m <<= 1) {
            float od = __shfl_xor(best, m, 64);
            int   oi = __shfl_xor(bidx, m, 64);
            if (od < best || (od == best && oi < bidx)) { best = od; bidx = oi; }
        }
        if (l == 0) {
            dout[IDX_OFF + tok] = (float)bidx;
            loss2[tok] = best;
        }
    }
}

// ---------------- loss reduction (fixed order) ----------------
__global__ __launch_bounds__(256) void vq_sum(const float* __restrict__ loss2,
                                              float* __restrict__ part) {
    __shared__ float ws[4];
    float s = 0.f;
#pragma unroll
    for (int q = 0; q < 4; ++q)
        s += loss2[blockIdx.x * 1024 + q * 256 + threadIdx.x];
#pragma unroll
    for (int m = 1; m < 64; m <<= 1) s += __shfl_xor(s, m, 64);
    if ((threadIdx.x & 63) == 0) ws[threadIdx.x >> 6] = s;
    __syncthreads();
    if (threadIdx.x == 0) part[blockIdx.x] = ws[0] + ws[1] + ws[2] + ws[3];
}

__global__ __launch_bounds__(64) void vq_final(const float* __restrict__ part,
                                               float* __restrict__ dout) {
    double s = (double)part[threadIdx.x];
#pragma unroll
    for (int m = 1; m < 64; m <<= 1) s += __shfl_xor(s, m, 64);
    if (threadIdx.x == 0) dout[LOSS_OFF] = (float)(s * 1.25 / 16777216.0);
}

// ---------------- gather z_q rows (after all scratch consumed) ----------------
__global__ __launch_bounds__(256) void vq_gather(const float* __restrict__ emb,
                                                 float* __restrict__ dout) {
    const int w = threadIdx.x >> 6, l = threadIdx.x & 63;
    for (int tok = blockIdx.x * 4 + w; tok < NTOK; tok += 2048 * 4) {
        int widx = (int)dout[IDX_OFF + tok];
        float4 ev = *(const float4*)&emb[(size_t)widx * DIM + l * 4];
        *(float4*)&dout[(size_t)tok * DIM + l * 4] = ev;
    }
}

extern "C" void kernel_launch(void* const* d_in, const int* in_sizes, int n_in,
                              void* d_out, int out_size, void* d_ws, size_t ws_size,
                              hipStream_t stream) {
    const float* z   = (const float*)d_in[0];
    const float* emb = (const float*)d_in[1];
    float* out = (float*)d_out;

    float* zsq   = out + SC_ZSQ;
    float* a1    = out + SC_A1;
    float* loss2 = out + SC_LOSS2;
    float* esq   = out + SC_ESQ;
    float* esqnh = out + SC_ESQNH;
    float* part  = out + SC_PART;
    int*   wcnt  = (int*)(out + SC_WCNT);
    int*   wcnt2 = (int*)(out + SC_WCNT2);
    int*   cntg  = (int*)(out + SC_CNTG);
    int*   listsg= (int*)(out + SC_LISTS);
    int*   wlist = (int*)(out + SC_WLIST);
    int*   wlist2= (int*)(out + SC_WLIST2);
    unsigned short* img  = (unsigned short*)(out + SC_EHIMG);
    unsigned short* zimg = (unsigned short*)(out + SC_ZIMG);

    vq_prep_esq <<<64,   256, 0, stream>>>(emb, esq, esqnh, wcnt, wcnt2);
    vq_prep_z   <<<4096, 256, 0, stream>>>(z, zsq, zimg);
    vq_prep_eimg<<<32,   256, 0, stream>>>(emb, img);
    vq_gemm<1>  <<<1024, 256, 0, stream>>>(zimg, img, esqnh, zsq, a1, wcnt, wlist, cntg, listsg, loss2, out);
    vq_gemm<2>  <<<1024, 256, 0, stream>>>(zimg, img, esqnh, zsq, a1, wcnt, wlist, cntg, listsg, loss2, out);
    vq_decide_hard<<<128, 256, 0, stream>>>(z, emb, zsq, esq, wcnt, wlist, cntg, listsg, wcnt2, wlist2, loss2, out);
    vq_decide_scan<<<64,  256, 0, stream>>>(z, emb, zsq, esq, wcnt2, wlist2, loss2, out);
    vq_sum      <<<64,   256, 0, stream>>>(loss2, part);
    vq_final    <<<1,    64,  0, stream>>>(part, out);
    vq_gather   <<<2048, 256, 0, stream>>>(emb, out);
}

// Round 8
// 242.805 us; speedup vs baseline: 1.5161x; 1.5161x over previous
//
#include <hip/hip_runtime.h>
#include <hip/hip_bf16.h>

#define NTOK   65536
#define KCODES 1024
#define DIM    256
#define LOSS_OFF ((size_t)NTOK * DIM)
#define IDX_OFF  (LOSS_OFF + 1)

#define MARGA 2e-4f     // a-space margin: >=13 sigma of bf16 dot noise

// ---- scratch layout inside the z_q output region (float-slot offsets) ----
#define SC_ZSQ    0              // 65536 f
#define SC_A1     65536          // 65536 f
#define SC_LOSS2  131072         // 65536 f
#define SC_ESQ    196608         // 1024 f
#define SC_ESQNH  197632         // 1024 f
#define SC_PART   198656         // 64 f
#define SC_WCNT   198720         // 1 int
#define SC_WCNT2  198721         // 1 int
#define SC_CNTG   198784         // 65536 int
#define SC_LISTS  264320         // 524288 int (8 per token)
#define SC_WLIST  788608         // 65536 int
#define SC_WLIST2 854144         // 4096 int
#define SC_EHIMG  858240         // 131072 f-slots = 512 KB bf16 emb image
#define SC_ZIMG   989312         // 8388608 f-slots = 32 MB bf16 z image

typedef __attribute__((ext_vector_type(8))) short short8;
typedef __attribute__((ext_vector_type(4))) float f32x4;

__device__ __forceinline__ unsigned f2bf(float x) {
    unsigned u = __float_as_uint(x);
    return (u + 0x7FFFu + ((u >> 16) & 1u)) >> 16;   // RNE
}

__device__ __forceinline__ void gload16(const void* g, void* l) {
    __builtin_amdgcn_global_load_lds((const __attribute__((address_space(1))) unsigned int*)g,
                                     (__attribute__((address_space(3))) unsigned int*)l,
                                     16, 0, 0);
}

// 4 interleaved faithful fp32 dot chains (each single-acc, ascending k — validated)
__device__ __forceinline__ float4 quad_dot(const float* __restrict__ z,
                                           const float* __restrict__ emb,
                                           int tok, int c0, int c1, int c2, int c3) {
    float a0 = 0.f, a1v = 0.f, a2 = 0.f, a3 = 0.f;
    const float4* zr = (const float4*)(z + (size_t)tok * DIM);
    const float4* e0 = (const float4*)(emb + (size_t)c0 * DIM);
    const float4* e1 = (const float4*)(emb + (size_t)c1 * DIM);
    const float4* e2 = (const float4*)(emb + (size_t)c2 * DIM);
    const float4* e3 = (const float4*)(emb + (size_t)c3 * DIM);
#pragma unroll
    for (int seg = 0; seg < 4; ++seg) {
        float4 zb[16];
#pragma unroll
        for (int qq = 0; qq < 16; ++qq) zb[qq] = zr[seg * 16 + qq];
#pragma unroll
        for (int qq = 0; qq < 16; ++qq) {
            float4 a = zb[qq];
            float4 b0 = e0[seg * 16 + qq], b1 = e1[seg * 16 + qq];
            float4 b2 = e2[seg * 16 + qq], b3 = e3[seg * 16 + qq];
            a0 = fmaf(a.x, b0.x, a0); a0 = fmaf(a.y, b0.y, a0);
            a0 = fmaf(a.z, b0.z, a0); a0 = fmaf(a.w, b0.w, a0);
            a1v = fmaf(a.x, b1.x, a1v); a1v = fmaf(a.y, b1.y, a1v);
            a1v = fmaf(a.z, b1.z, a1v); a1v = fmaf(a.w, b1.w, a1v);
            a2 = fmaf(a.x, b2.x, a2); a2 = fmaf(a.y, b2.y, a2);
            a2 = fmaf(a.z, b2.z, a2); a2 = fmaf(a.w, b2.w, a2);
            a3 = fmaf(a.x, b3.x, a3); a3 = fmaf(a.y, b3.y, a3);
            a3 = fmaf(a.z, b3.z, a3); a3 = fmaf(a.w, b3.w, a3);
        }
    }
    return make_float4(a0, a1v, a2, a3);
}

// wave-parallel numpy pairwise sum-of-squares replica (16 lanes per 256-row)
__device__ __forceinline__ float np_rowsq256_wave(const float* row, int sub) {
    const int j = sub & 7, half = sub >> 3;
    const float* a = row + half * 128 + j;
    float r = 0.f;
#pragma unroll
    for (int i = 0; i < 16; ++i) {
        float v = a[i * 8];
        float sq = v * v;
        asm volatile("" : "+v"(sq));
        r += sq;
    }
    float t = r + __shfl_xor(r, 1, 64);
    t = t + __shfl_xor(t, 2, 64);
    t = t + __shfl_xor(t, 4, 64);
    t = t + __shfl_xor(t, 8, 64);
    return t;
}

// ---------------- prep: esq / esqnh (+ worklist counters reset) ----------------
__global__ __launch_bounds__(256) void vq_prep_esq(const float* __restrict__ emb,
                                                   float* __restrict__ esq,
                                                   float* __restrict__ esqnh,
                                                   int* __restrict__ wcnt,
                                                   int* __restrict__ wcnt2) {
    if (blockIdx.x == 0 && threadIdx.x == 0) { *wcnt = 0; *wcnt2 = 0; }
    int code = blockIdx.x * 16 + (threadIdx.x >> 4);   // grid 64
    int sub = threadIdx.x & 15;
    float tot = np_rowsq256_wave(emb + (size_t)code * DIM, sub);
    if (sub == 0) { esq[code] = tot; esqnh[code] = -0.5f * tot; }
}

// ---------------- prep: zsq (np-faithful) + pre-swizzled bf16 z image ----------------
__global__ __launch_bounds__(256) void vq_prep_z(const float* __restrict__ z,
                                                 float* __restrict__ zsq,
                                                 unsigned short* __restrict__ zimg) {
    int tok = blockIdx.x * 16 + (threadIdx.x >> 4);    // grid 4096
    int sub = threadIdx.x & 15;
    float tot = np_rowsq256_wave(z + (size_t)tok * DIM, sub);
    if (sub == 0) zsq[tok] = tot;

    const float* src = z + (size_t)tok * DIM + sub * 16;
    float4 v0 = *(const float4*)&src[0],  v1 = *(const float4*)&src[4];
    float4 v2 = *(const float4*)&src[8],  v3 = *(const float4*)&src[12];
    uint4 p0, p1;
    p0.x = f2bf(v0.x) | (f2bf(v0.y) << 16);  p0.y = f2bf(v0.z) | (f2bf(v0.w) << 16);
    p0.z = f2bf(v1.x) | (f2bf(v1.y) << 16);  p0.w = f2bf(v1.z) | (f2bf(v1.w) << 16);
    p1.x = f2bf(v2.x) | (f2bf(v2.y) << 16);  p1.y = f2bf(v2.z) | (f2bf(v2.w) << 16);
    p1.z = f2bf(v3.x) | (f2bf(v3.y) << 16);  p1.w = f2bf(v3.z) | (f2bf(v3.w) << 16);
    int bid = tok >> 6, tl = tok & 63;
    char* base = (char*)zimg + (size_t)bid * 32768 + tl * 512;
    int g0 = sub * 2, g1 = sub * 2 + 1;
    *(uint4*)(base + ((g0 * 16) ^ ((tl & 7) << 4))) = p0;
    *(uint4*)(base + ((g1 * 16) ^ ((tl & 7) << 4))) = p1;
}

// ---------------- prep: bf16 emb image in pre-swizzled LDS slice layout ----------------
__global__ __launch_bounds__(256) void vq_prep_eimg(const float* __restrict__ emb,
                                                    unsigned short* __restrict__ img) {
    int job = blockIdx.x * 256 + threadIdx.x;   // grid 32
    int code = job >> 3, ks = job & 7;
    int cc = (code >> 6) & 3, lcl = (code >> 8) * 64 + (code & 63);
    const float* src = emb + (size_t)code * DIM + ks * 32;
    char* base = (char*)img + (size_t)(cc * 8 + ks) * 16384;
#pragma unroll
    for (int q = 0; q < 4; ++q) {
        float4 v0 = *(const float4*)&src[q * 8];
        float4 v1 = *(const float4*)&src[q * 8 + 4];
        uint4 p;
        p.x = f2bf(v0.x) | (f2bf(v0.y) << 16);
        p.y = f2bf(v0.z) | (f2bf(v0.w) << 16);
        p.z = f2bf(v1.x) | (f2bf(v1.y) << 16);
        p.w = f2bf(v1.z) | (f2bf(v1.w) << 16);
        *(uint4*)(base + lcl * 64 + ((q * 16) ^ (((lcl >> 1) & 3) << 4))) = p;
    }
}

// ---------------- GEMM filter: PASS1 = per-token max(a); PASS2 = enumerate+finalize ----------------
template<int PASS>
__global__ __launch_bounds__(256, 2) void vq_gemm(const unsigned short* __restrict__ zimg,
                                                  const unsigned short* __restrict__ img,
                                                  const float* __restrict__ esqnh,
                                                  const float* __restrict__ zsq,
                                                  float* __restrict__ a1,
                                                  int* __restrict__ wcnt,
                                                  int* __restrict__ wlist,
                                                  int* __restrict__ cntg,
                                                  int* __restrict__ listsg,
                                                  float* __restrict__ loss2,
                                                  float* __restrict__ dout) {
    __shared__ __align__(16) short zh_s[64 * 256];    // 32 KB
    __shared__ __align__(16) short eh_s[2][8192];     // 2 x 16 KB
    __shared__ float a1w_s[4][64];
    __shared__ int cnt_s[64];
    __shared__ int lists_s[512];                      // 8 per token

    const int tid = threadIdx.x, bid = blockIdx.x;
    const int w = tid >> 6, l = tid & 63;
    const int t0 = bid * 64;

    {
        const char* gz = (const char*)zimg + (size_t)bid * 32768 + w * 8192 + l * 16;
        char* lz = (char*)zh_s + w * 8192;
#pragma unroll
        for (int i = 0; i < 8; ++i) gload16(gz + i * 1024, lz + i * 1024);
    }
    if (PASS == 2 && tid < 64) cnt_s[tid] = 0;
    {
        const char* gs = (const char*)img + w * 4096 + l * 16;
        char* ld = (char*)&eh_s[0][0] + w * 4096;
#pragma unroll
        for (int i = 0; i < 4; ++i) gload16(gs + i * 1024, ld + i * 1024);
    }
    __syncthreads();

    float thrv[4], amax[4];
#pragma unroll
    for (int tf = 0; tf < 4; ++tf) {
        amax[tf] = -3.4e38f;
        if (PASS == 2) thrv[tf] = a1[t0 + tf * 16 + (l & 15)] - MARGA;
    }

    f32x4 acc[4][4];

    for (int c = 0; c < 4; ++c) {
#pragma unroll
        for (int f = 0; f < 4; ++f) {
            f32x4 e4 = *(const f32x4*)&esqnh[w * 256 + c * 64 + f * 16 + (l >> 4) * 4];
#pragma unroll
            for (int tf = 0; tf < 4; ++tf) acc[f][tf] = e4;
        }
        for (int ks = 0; ks < 8; ++ks) {
            int s = c * 8 + ks, buf = s & 1;
            if (s < 31) {
                const char* gs = (const char*)img + (size_t)(s + 1) * 16384 + w * 4096 + l * 16;
                char* ld = (char*)&eh_s[buf ^ 1][0] + w * 4096;
#pragma unroll
                for (int i = 0; i < 4; ++i) gload16(gs + i * 1024, ld + i * 1024);
            }
            short8 bfr[4], afr[4];
#pragma unroll
            for (int tf = 0; tf < 4; ++tf) {
                int tokl = tf * 16 + (l & 15);
                int byte = tokl * 512 + ((ks * 64 + (l >> 4) * 16) ^ ((tokl & 7) << 4));
                bfr[tf] = *(short8*)((char*)zh_s + byte);
            }
#pragma unroll
            for (int f = 0; f < 4; ++f) {
                int lcl = w * 64 + f * 16 + (l & 15);
                int byte = lcl * 64 + (((l >> 4) * 16) ^ (((lcl >> 1) & 3) << 4));
                afr[f] = *(short8*)((char*)&eh_s[buf][0] + byte);
            }
#pragma unroll
            for (int f = 0; f < 4; ++f)
#pragma unroll
                for (int tf = 0; tf < 4; ++tf)
                    acc[f][tf] = __builtin_amdgcn_mfma_f32_16x16x32_bf16(
                        afr[f], bfr[tf], acc[f][tf], 0, 0, 0);
            __syncthreads();
        }
        if (PASS == 1) {
#pragma unroll
            for (int tf = 0; tf < 4; ++tf) {
                float m0 = fmaxf(fmaxf(acc[0][tf][0], acc[0][tf][1]), fmaxf(acc[0][tf][2], acc[0][tf][3]));
                float m1 = fmaxf(fmaxf(acc[1][tf][0], acc[1][tf][1]), fmaxf(acc[1][tf][2], acc[1][tf][3]));
                float m2 = fmaxf(fmaxf(acc[2][tf][0], acc[2][tf][1]), fmaxf(acc[2][tf][2], acc[2][tf][3]));
                float m3 = fmaxf(fmaxf(acc[3][tf][0], acc[3][tf][1]), fmaxf(acc[3][tf][2], acc[3][tf][3]));
                amax[tf] = fmaxf(amax[tf], fmaxf(fmaxf(m0, m1), fmaxf(m2, m3)));
            }
        } else {
#pragma unroll
            for (int tf = 0; tf < 4; ++tf) {
                int tokl = tf * 16 + (l & 15);
#pragma unroll
                for (int f = 0; f < 4; ++f)
#pragma unroll
                    for (int r = 0; r < 4; ++r) {
                        float a = acc[f][tf][r];
                        if (a >= thrv[tf]) {
                            int code = w * 256 + c * 64 + f * 16 + (l >> 4) * 4 + r;
                            int pos = atomicAdd(&cnt_s[tokl], 1);
                            if (pos < 8) lists_s[tokl * 8 + pos] = code;
                        }
                    }
            }
        }
    }

    if (PASS == 1) {
#pragma unroll
        for (int tf = 0; tf < 4; ++tf) {
            float m = amax[tf];
            m = fmaxf(m, __shfl_xor(m, 16, 64));
            m = fmaxf(m, __shfl_xor(m, 32, 64));
            if (l < 16) a1w_s[w][tf * 16 + l] = m;
        }
        __syncthreads();
        if (tid < 64)
            a1[t0 + tid] = fmaxf(fmaxf(a1w_s[0][tid], a1w_s[1][tid]),
                                 fmaxf(a1w_s[2][tid], a1w_s[3][tid]));
    } else {
        __syncthreads();
        if (tid < 64) {
            int t = t0 + tid, ct = cnt_s[tid];
            if (ct == 1) {
                dout[IDX_OFF + t] = (float)lists_s[tid * 8];
                loss2[t] = fmaf(-2.f, a1[t], zsq[t]);
            } else {
                int pos = atomicAdd(wcnt, 1);
                wlist[pos] = t;
                cntg[t] = ct;
                int m = ct < 8 ? ct : 8;
                for (int i = 0; i < m; ++i) listsg[t * 8 + i] = lists_s[tid * 8 + i];
            }
        }
    }
}

// ---------------- decide (hard): thread per token, up to 8 candidates ----------------
__global__ __launch_bounds__(256) void vq_decide_hard(const float* __restrict__ z,
                                                      const float* __restrict__ emb,
                                                      const float* __restrict__ zsq,
                                                      const float* __restrict__ esq,
                                                      const int* __restrict__ wcnt,
                                                      const int* __restrict__ wlist,
                                                      const int* __restrict__ cntg,
                                                      const int* __restrict__ listsg,
                                                      int* __restrict__ wcnt2,
                                                      int* __restrict__ wlist2,
                                                      float* __restrict__ loss2,
                                                      float* __restrict__ dout) {
    const int n = wcnt[0];
    for (int q = blockIdx.x * 256 + threadIdx.x; q < n; q += 256 * 256) {
        int tok = wlist[q];
        int ct = cntg[tok];
        if (ct == 0 || ct > 8) {
            int p = atomicAdd(wcnt2, 1);
            if (p < 4096) wlist2[p] = tok;
            continue;
        }
        int cand[8];
        cand[0] = listsg[tok * 8];
#pragma unroll
        for (int i = 1; i < 8; ++i) cand[i] = (i < ct) ? listsg[tok * 8 + i] : cand[0];
        float zq = zsq[tok];

        float4 g0 = quad_dot(z, emb, tok, cand[0], cand[1], cand[2], cand[3]);
        float d0 = (zq + esq[cand[0]]) - 2.0f * g0.x;
        float d1 = (zq + esq[cand[1]]) - 2.0f * g0.y;
        float d2 = (zq + esq[cand[2]]) - 2.0f * g0.z;
        float d3 = (zq + esq[cand[3]]) - 2.0f * g0.w;
        float db = d0; int cb = cand[0];
        if (ct > 1 && (d1 < db || (d1 == db && cand[1] < cb))) { db = d1; cb = cand[1]; }
        if (ct > 2 && (d2 < db || (d2 == db && cand[2] < cb))) { db = d2; cb = cand[2]; }
        if (ct > 3 && (d3 < db || (d3 == db && cand[3] < cb))) { db = d3; cb = cand[3]; }
        if (ct > 4) {
            float4 g1 = quad_dot(z, emb, tok, cand[4], cand[5], cand[6], cand[7]);
            float d4 = (zq + esq[cand[4]]) - 2.0f * g1.x;
            float d5 = (zq + esq[cand[5]]) - 2.0f * g1.y;
            float d6 = (zq + esq[cand[6]]) - 2.0f * g1.z;
            float d7 = (zq + esq[cand[7]]) - 2.0f * g1.w;
            if (d4 < db || (d4 == db && cand[4] < cb)) { db = d4; cb = cand[4]; }
            if (ct > 5 && (d5 < db || (d5 == db && cand[5] < cb))) { db = d5; cb = cand[5]; }
            if (ct > 6 && (d6 < db || (d6 == db && cand[6] < cb))) { db = d6; cb = cand[6]; }
            if (ct > 7 && (d7 < db || (d7 == db && cand[7] < cb))) { db = d7; cb = cand[7]; }
        }
        dout[IDX_OFF + tok] = (float)cb;
        loss2[tok] = db;
    }
}

// ---------------- decide (scan): BLOCK per token, full 1024 faithful scan ----------------
__global__ __launch_bounds__(256) void vq_decide_scan(const float* __restrict__ z,
                                                      const float* __restrict__ emb,
                                                      const float* __restrict__ zsq,
                                                      const float* __restrict__ esq,
                                                      const int* __restrict__ wcnt2,
                                                      const int* __restrict__ wlist2,
                                                      float* __restrict__ loss2,
                                                      float* __restrict__ dout) {
    __shared__ __align__(16) float zrow[DIM];
    __shared__ float dred[256];
    __shared__ int   ired[256];
    int n = wcnt2[0];
    if (n > 4096) n = 4096;
    const int tid = threadIdx.x;
    for (int job = blockIdx.x; job < n; job += 64) {
        int tok = wlist2[job];
        __syncthreads();
        if (tid < 64) ((float4*)zrow)[tid] = ((const float4*)(z + (size_t)tok * DIM))[tid];
        __syncthreads();
        float zq = zsq[tok];
        // 4 interleaved chains: codes tid, tid+256, tid+512, tid+768 (ascending)
        float a0 = 0.f, a1v = 0.f, a2 = 0.f, a3 = 0.f;
        const float4* e0 = (const float4*)(emb + (size_t)(tid      ) * DIM);
        const float4* e1 = (const float4*)(emb + (size_t)(tid + 256) * DIM);
        const float4* e2 = (const float4*)(emb + (size_t)(tid + 512) * DIM);
        const float4* e3 = (const float4*)(emb + (size_t)(tid + 768) * DIM);
#pragma unroll
        for (int seg = 0; seg < 4; ++seg) {
            float4 zb[16];
#pragma unroll
            for (int qq = 0; qq < 16; ++qq) zb[qq] = ((float4*)zrow)[seg * 16 + qq];
#pragma unroll
            for (int qq = 0; qq < 16; ++qq) {
                float4 a = zb[qq];
                float4 b0 = e0[seg * 16 + qq], b1 = e1[seg * 16 + qq];
                float4 b2 = e2[seg * 16 + qq], b3 = e3[seg * 16 + qq];
                a0 = fmaf(a.x, b0.x, a0); a0 = fmaf(a.y, b0.y, a0);
                a0 = fmaf(a.z, b0.z, a0); a0 = fmaf(a.w, b0.w, a0);
                a1v = fmaf(a.x, b1.x, a1v); a1v = fmaf(a.y, b1.y, a1v);
                a1v = fmaf(a.z, b1.z, a1v); a1v = fmaf(a.w, b1.w, a1v);
                a2 = fmaf(a.x, b2.x, a2); a2 = fmaf(a.y, b2.y, a2);
                a2 = fmaf(a.z, b2.z, a2); a2 = fmaf(a.w, b2.w, a2);
                a3 = fmaf(a.x, b3.x, a3); a3 = fmaf(a.y, b3.y, a3);
                a3 = fmaf(a.z, b3.z, a3); a3 = fmaf(a.w, b3.w, a3);
            }
        }
        float d0 = (zq + esq[tid      ]) - 2.0f * a0;
        float d1 = (zq + esq[tid + 256]) - 2.0f * a1v;
        float d2 = (zq + esq[tid + 512]) - 2.0f * a2;
        float d3 = (zq + esq[tid + 768]) - 2.0f * a3;
        float db = d0; int cb = tid;
        if (d1 < db) { db = d1; cb = tid + 256; }
        if (d2 < db) { db = d2; cb = tid + 512; }
        if (d3 < db) { db = d3; cb = tid + 768; }
        dred[tid] = db; ired[tid] = cb;
        __syncthreads();
        for (int step = 128; step >= 1; step >>= 1) {
            if (tid < step) {
                float od = dred[tid + step]; int oi = ired[tid + step];
                if (od < dred[tid] || (od == dred[tid] && oi < ired[tid])) {
                    dred[tid] = od; ired[tid] = oi;
                }
            }
            __syncthreads();
        }
        if (tid == 0) {
            dout[IDX_OFF + tok] = (float)ired[0];
            loss2[tok] = dred[0];
        }
    }
}

// ---------------- loss reduction (fixed order) ----------------
__global__ __launch_bounds__(256) void vq_sum(const float* __restrict__ loss2,
                                              float* __restrict__ part) {
    __shared__ float ws[4];
    float s = 0.f;
#pragma unroll
    for (int q = 0; q < 4; ++q)
        s += loss2[blockIdx.x * 1024 + q * 256 + threadIdx.x];
#pragma unroll
    for (int m = 1; m < 64; m <<= 1) s += __shfl_xor(s, m, 64);
    if ((threadIdx.x & 63) == 0) ws[threadIdx.x >> 6] = s;
    __syncthreads();
    if (threadIdx.x == 0) part[blockIdx.x] = ws[0] + ws[1] + ws[2] + ws[3];
}

__global__ __launch_bounds__(64) void vq_final(const float* __restrict__ part,
                                               float* __restrict__ dout) {
    double s = (double)part[threadIdx.x];
#pragma unroll
    for (int m = 1; m < 64; m <<= 1) s += __shfl_xor(s, m, 64);
    if (threadIdx.x == 0) dout[LOSS_OFF] = (float)(s * 1.25 / 16777216.0);
}

// ---------------- gather z_q rows ----------------
__global__ __launch_bounds__(256) void vq_gather(const float* __restrict__ emb,
                                                 float* __restrict__ dout) {
    const int w = threadIdx.x >> 6, l = threadIdx.x & 63;
    for (int tok = blockIdx.x * 4 + w; tok < NTOK; tok += 2048 * 4) {
        int widx = (int)dout[IDX_OFF + tok];
        float4 ev = *(const float4*)&emb[(size_t)widx * DIM + l * 4];
        *(float4*)&dout[(size_t)tok * DIM + l * 4] = ev;
    }
}

extern "C" void kernel_launch(void* const* d_in, const int* in_sizes, int n_in,
                              void* d_out, int out_size, void* d_ws, size_t ws_size,
                              hipStream_t stream) {
    const float* z   = (const float*)d_in[0];
    const float* emb = (const float*)d_in[1];
    float* out = (float*)d_out;

    float* zsq   = out + SC_ZSQ;
    float* a1    = out + SC_A1;
    float* loss2 = out + SC_LOSS2;
    float* esq   = out + SC_ESQ;
    float* esqnh = out + SC_ESQNH;
    float* part  = out + SC_PART;
    int*   wcnt  = (int*)(out + SC_WCNT);
    int*   wcnt2 = (int*)(out + SC_WCNT2);
    int*   cntg  = (int*)(out + SC_CNTG);
    int*   listsg= (int*)(out + SC_LISTS);
    int*   wlist = (int*)(out + SC_WLIST);
    int*   wlist2= (int*)(out + SC_WLIST2);
    unsigned short* img  = (unsigned short*)(out + SC_EHIMG);
    unsigned short* zimg = (unsigned short*)(out + SC_ZIMG);

    vq_prep_esq <<<64,   256, 0, stream>>>(emb, esq, esqnh, wcnt, wcnt2);
    vq_prep_z   <<<4096, 256, 0, stream>>>(z, zsq, zimg);
    vq_prep_eimg<<<32,   256, 0, stream>>>(emb, img);
    vq_gemm<1>  <<<1024, 256, 0, stream>>>(zimg, img, esqnh, zsq, a1, wcnt, wlist, cntg, listsg, loss2, out);
    vq_gemm<2>  <<<1024, 256, 0, stream>>>(zimg, img, esqnh, zsq, a1, wcnt, wlist, cntg, listsg, loss2, out);
    vq_decide_hard<<<256, 256, 0, stream>>>(z, emb, zsq, esq, wcnt, wlist, cntg, listsg, wcnt2, wlist2, loss2, out);
    vq_decide_scan<<<64,  256, 0, stream>>>(z, emb, zsq, esq, wcnt2, wlist2, loss2, out);
    vq_sum      <<<64,   256, 0, stream>>>(loss2, part);
    vq_final    <<<1,    64,  0, stream>>>(part, out);
    vq_gather   <<<2048, 256, 0, stream>>>(emb, out);
}

// Round 9
// 167.660 us; speedup vs baseline: 2.1956x; 1.4482x over previous
//
#include <hip/hip_runtime.h>
#include <hip/hip_bf16.h>

#define NTOK   65536
#define KCODES 1024
#define DIM    256
#define LOSS_OFF ((size_t)NTOK * DIM)
#define IDX_OFF  (LOSS_OFF + 1)

#define MARGA 2e-4f     // a-space margin (validated round 8)

// ---- scratch layout inside the z_q output region (float-slot offsets) ----
#define SC_ZSQ    0              // 65536 f
#define SC_A1     65536          // 65536 f
#define SC_LOSS2  131072         // 65536 f
#define SC_ESQ    196608         // 1024 f
#define SC_ESQNH  197632         // 1024 f
#define SC_PART   198656         // 64 f
#define SC_WCNT   198720         // 1 int
#define SC_WCNT2  198721         // 1 int
#define SC_CNTG   198784         // 65536 int
#define SC_LISTS  264320         // 524288 int (8 per token)
#define SC_WLIST  788608         // 65536 int
#define SC_WLIST2 854144         // 4096 int
#define SC_EHIMG  858240         // 131072 f-slots = 512 KB bf16 emb image
#define SC_ZIMG   989312         // 8388608 f-slots = 32 MB bf16 z image
#define SC_PAIRD  9377920        // 524288 f (per-pair faithful distances)

typedef __attribute__((ext_vector_type(8))) short short8;
typedef __attribute__((ext_vector_type(4))) float f32x4;

__device__ __forceinline__ unsigned f2bf(float x) {
    unsigned u = __float_as_uint(x);
    return (u + 0x7FFFu + ((u >> 16) & 1u)) >> 16;   // RNE
}

__device__ __forceinline__ void gload16(const void* g, void* l) {
    __builtin_amdgcn_global_load_lds((const __attribute__((address_space(1))) unsigned int*)g,
                                     (__attribute__((address_space(3))) unsigned int*)l,
                                     16, 0, 0);
}

// faithful fp32 distance (validated rounds 4-8): sequential single-acc FMA chain
__device__ __forceinline__ float faithful_d(const float* __restrict__ z,
                                            const float* __restrict__ emb,
                                            float zsq, float esq, int tok, int c) {
    const float4* zr = (const float4*)(z + (size_t)tok * DIM);
    const float4* er = (const float4*)(emb + (size_t)c * DIM);
    float acc = 0.f;
#pragma unroll 8
    for (int q = 0; q < 64; ++q) {
        float4 a = zr[q], b = er[q];
        acc = fmaf(a.x, b.x, acc); acc = fmaf(a.y, b.y, acc);
        acc = fmaf(a.z, b.z, acc); acc = fmaf(a.w, b.w, acc);
    }
    float t1 = zsq + esq;
    return t1 - 2.0f * acc;
}

// wave-parallel numpy pairwise sum-of-squares replica (16 lanes per 256-row)
__device__ __forceinline__ float np_rowsq256_wave(const float* row, int sub) {
    const int j = sub & 7, half = sub >> 3;
    const float* a = row + half * 128 + j;
    float r = 0.f;
#pragma unroll
    for (int i = 0; i < 16; ++i) {
        float v = a[i * 8];
        float sq = v * v;
        asm volatile("" : "+v"(sq));
        r += sq;
    }
    float t = r + __shfl_xor(r, 1, 64);
    t = t + __shfl_xor(t, 2, 64);
    t = t + __shfl_xor(t, 4, 64);
    t = t + __shfl_xor(t, 8, 64);
    return t;
}

// ---------------- prep: esq / esqnh (+ worklist counters reset) ----------------
__global__ __launch_bounds__(256) void vq_prep_esq(const float* __restrict__ emb,
                                                   float* __restrict__ esq,
                                                   float* __restrict__ esqnh,
                                                   int* __restrict__ wcnt,
                                                   int* __restrict__ wcnt2) {
    if (blockIdx.x == 0 && threadIdx.x == 0) { *wcnt = 0; *wcnt2 = 0; }
    int code = blockIdx.x * 16 + (threadIdx.x >> 4);   // grid 64
    int sub = threadIdx.x & 15;
    float tot = np_rowsq256_wave(emb + (size_t)code * DIM, sub);
    if (sub == 0) { esq[code] = tot; esqnh[code] = -0.5f * tot; }
}

// ---------------- prep: zsq (np-faithful) + pre-swizzled bf16 z image ----------------
__global__ __launch_bounds__(256) void vq_prep_z(const float* __restrict__ z,
                                                 float* __restrict__ zsq,
                                                 unsigned short* __restrict__ zimg) {
    int tok = blockIdx.x * 16 + (threadIdx.x >> 4);    // grid 4096
    int sub = threadIdx.x & 15;
    float tot = np_rowsq256_wave(z + (size_t)tok * DIM, sub);
    if (sub == 0) zsq[tok] = tot;

    const float* src = z + (size_t)tok * DIM + sub * 16;
    float4 v0 = *(const float4*)&src[0],  v1 = *(const float4*)&src[4];
    float4 v2 = *(const float4*)&src[8],  v3 = *(const float4*)&src[12];
    uint4 p0, p1;
    p0.x = f2bf(v0.x) | (f2bf(v0.y) << 16);  p0.y = f2bf(v0.z) | (f2bf(v0.w) << 16);
    p0.z = f2bf(v1.x) | (f2bf(v1.y) << 16);  p0.w = f2bf(v1.z) | (f2bf(v1.w) << 16);
    p1.x = f2bf(v2.x) | (f2bf(v2.y) << 16);  p1.y = f2bf(v2.z) | (f2bf(v2.w) << 16);
    p1.z = f2bf(v3.x) | (f2bf(v3.y) << 16);  p1.w = f2bf(v3.z) | (f2bf(v3.w) << 16);
    int bid = tok >> 6, tl = tok & 63;
    char* base = (char*)zimg + (size_t)bid * 32768 + tl * 512;
    int g0 = sub * 2, g1 = sub * 2 + 1;
    *(uint4*)(base + ((g0 * 16) ^ ((tl & 7) << 4))) = p0;
    *(uint4*)(base + ((g1 * 16) ^ ((tl & 7) << 4))) = p1;
}

// ---------------- prep: bf16 emb image in pre-swizzled LDS slice layout ----------------
__global__ __launch_bounds__(256) void vq_prep_eimg(const float* __restrict__ emb,
                                                    unsigned short* __restrict__ img) {
    int job = blockIdx.x * 256 + threadIdx.x;   // grid 32
    int code = job >> 3, ks = job & 7;
    int cc = (code >> 6) & 3, lcl = (code >> 8) * 64 + (code & 63);
    const float* src = emb + (size_t)code * DIM + ks * 32;
    char* base = (char*)img + (size_t)(cc * 8 + ks) * 16384;
#pragma unroll
    for (int q = 0; q < 4; ++q) {
        float4 v0 = *(const float4*)&src[q * 8];
        float4 v1 = *(const float4*)&src[q * 8 + 4];
        uint4 p;
        p.x = f2bf(v0.x) | (f2bf(v0.y) << 16);
        p.y = f2bf(v0.z) | (f2bf(v0.w) << 16);
        p.z = f2bf(v1.x) | (f2bf(v1.y) << 16);
        p.w = f2bf(v1.z) | (f2bf(v1.w) << 16);
        *(uint4*)(base + lcl * 64 + ((q * 16) ^ (((lcl >> 1) & 3) << 4))) = p;
    }
}

// ---------------- GEMM filter: PASS1 = per-token max(a); PASS2 = enumerate+finalize ----------------
template<int PASS>
__global__ __launch_bounds__(256, 2) void vq_gemm(const unsigned short* __restrict__ zimg,
                                                  const unsigned short* __restrict__ img,
                                                  const float* __restrict__ esqnh,
                                                  const float* __restrict__ zsq,
                                                  float* __restrict__ a1,
                                                  int* __restrict__ wcnt,
                                                  int* __restrict__ wlist,
                                                  int* __restrict__ cntg,
                                                  int* __restrict__ listsg,
                                                  float* __restrict__ loss2,
                                                  float* __restrict__ dout) {
    __shared__ __align__(16) short zh_s[64 * 256];    // 32 KB
    __shared__ __align__(16) short eh_s[2][8192];     // 2 x 16 KB
    __shared__ float a1w_s[4][64];
    __shared__ int cnt_s[64];
    __shared__ int lists_s[512];                      // 8 per token

    const int tid = threadIdx.x, bid = blockIdx.x;
    const int w = tid >> 6, l = tid & 63;
    const int t0 = bid * 64;

    {
        const char* gz = (const char*)zimg + (size_t)bid * 32768 + w * 8192 + l * 16;
        char* lz = (char*)zh_s + w * 8192;
#pragma unroll
        for (int i = 0; i < 8; ++i) gload16(gz + i * 1024, lz + i * 1024);
    }
    if (PASS == 2 && tid < 64) cnt_s[tid] = 0;
    {
        const char* gs = (const char*)img + w * 4096 + l * 16;
        char* ld = (char*)&eh_s[0][0] + w * 4096;
#pragma unroll
        for (int i = 0; i < 4; ++i) gload16(gs + i * 1024, ld + i * 1024);
    }
    __syncthreads();

    float thrv[4], amax[4];
#pragma unroll
    for (int tf = 0; tf < 4; ++tf) {
        amax[tf] = -3.4e38f;
        if (PASS == 2) thrv[tf] = a1[t0 + tf * 16 + (l & 15)] - MARGA;
    }

    f32x4 acc[4][4];

    for (int c = 0; c < 4; ++c) {
#pragma unroll
        for (int f = 0; f < 4; ++f) {
            f32x4 e4 = *(const f32x4*)&esqnh[w * 256 + c * 64 + f * 16 + (l >> 4) * 4];
#pragma unroll
            for (int tf = 0; tf < 4; ++tf) acc[f][tf] = e4;
        }
        for (int ks = 0; ks < 8; ++ks) {
            int s = c * 8 + ks, buf = s & 1;
            if (s < 31) {
                const char* gs = (const char*)img + (size_t)(s + 1) * 16384 + w * 4096 + l * 16;
                char* ld = (char*)&eh_s[buf ^ 1][0] + w * 4096;
#pragma unroll
                for (int i = 0; i < 4; ++i) gload16(gs + i * 1024, ld + i * 1024);
            }
            short8 bfr[4], afr[4];
#pragma unroll
            for (int tf = 0; tf < 4; ++tf) {
                int tokl = tf * 16 + (l & 15);
                int byte = tokl * 512 + ((ks * 64 + (l >> 4) * 16) ^ ((tokl & 7) << 4));
                bfr[tf] = *(short8*)((char*)zh_s + byte);
            }
#pragma unroll
            for (int f = 0; f < 4; ++f) {
                int lcl = w * 64 + f * 16 + (l & 15);
                int byte = lcl * 64 + (((l >> 4) * 16) ^ (((lcl >> 1) & 3) << 4));
                afr[f] = *(short8*)((char*)&eh_s[buf][0] + byte);
            }
#pragma unroll
            for (int f = 0; f < 4; ++f)
#pragma unroll
                for (int tf = 0; tf < 4; ++tf)
                    acc[f][tf] = __builtin_amdgcn_mfma_f32_16x16x32_bf16(
                        afr[f], bfr[tf], acc[f][tf], 0, 0, 0);
            __syncthreads();
        }
        if (PASS == 1) {
#pragma unroll
            for (int tf = 0; tf < 4; ++tf) {
                float m0 = fmaxf(fmaxf(acc[0][tf][0], acc[0][tf][1]), fmaxf(acc[0][tf][2], acc[0][tf][3]));
                float m1 = fmaxf(fmaxf(acc[1][tf][0], acc[1][tf][1]), fmaxf(acc[1][tf][2], acc[1][tf][3]));
                float m2 = fmaxf(fmaxf(acc[2][tf][0], acc[2][tf][1]), fmaxf(acc[2][tf][2], acc[2][tf][3]));
                float m3 = fmaxf(fmaxf(acc[3][tf][0], acc[3][tf][1]), fmaxf(acc[3][tf][2], acc[3][tf][3]));
                amax[tf] = fmaxf(amax[tf], fmaxf(fmaxf(m0, m1), fmaxf(m2, m3)));
            }
        } else {
#pragma unroll
            for (int tf = 0; tf < 4; ++tf) {
                int tokl = tf * 16 + (l & 15);
#pragma unroll
                for (int f = 0; f < 4; ++f)
#pragma unroll
                    for (int r = 0; r < 4; ++r) {
                        float a = acc[f][tf][r];
                        if (a >= thrv[tf]) {
                            int code = w * 256 + c * 64 + f * 16 + (l >> 4) * 4 + r;
                            int pos = atomicAdd(&cnt_s[tokl], 1);
                            if (pos < 8) lists_s[tokl * 8 + pos] = code;
                        }
                    }
            }
        }
    }

    if (PASS == 1) {
#pragma unroll
        for (int tf = 0; tf < 4; ++tf) {
            float m = amax[tf];
            m = fmaxf(m, __shfl_xor(m, 16, 64));
            m = fmaxf(m, __shfl_xor(m, 32, 64));
            if (l < 16) a1w_s[w][tf * 16 + l] = m;
        }
        __syncthreads();
        if (tid < 64)
            a1[t0 + tid] = fmaxf(fmaxf(a1w_s[0][tid], a1w_s[1][tid]),
                                 fmaxf(a1w_s[2][tid], a1w_s[3][tid]));
    } else {
        __syncthreads();
        if (tid < 64) {
            int t = t0 + tid, ct = cnt_s[tid];
            if (ct == 1) {
                dout[IDX_OFF + t] = (float)lists_s[tid * 8];
                loss2[t] = fmaf(-2.f, a1[t], zsq[t]);
            } else {
                int pos = atomicAdd(wcnt, 1);
                wlist[pos] = t;
                cntg[t] = ct;
                int m = ct < 8 ? ct : 8;
                for (int i = 0; i < m; ++i) listsg[t * 8 + i] = lists_s[tid * 8 + i];
            }
        }
    }
}

// ---------------- pairs: one LANE per (hard-token, candidate) pair ----------------
// 8 consecutive lanes share a token -> z-row loads coalesce/broadcast; each lane
// runs the validated faithful sequential chain for its candidate.
__global__ __launch_bounds__(256) void vq_pairs(const float* __restrict__ z,
                                                const float* __restrict__ emb,
                                                const float* __restrict__ zsq,
                                                const float* __restrict__ esq,
                                                const int* __restrict__ wcnt,
                                                const int* __restrict__ wlist,
                                                const int* __restrict__ cntg,
                                                const int* __restrict__ listsg,
                                                int* __restrict__ wcnt2,
                                                int* __restrict__ wlist2,
                                                float* __restrict__ paird) {
    const int n = wcnt[0];
    const int total = 8 * n;
    for (int p = blockIdx.x * 256 + threadIdx.x; p < total; p += 2048 * 256) {
        int q = p >> 3, slot = p & 7;
        int tok = wlist[q];
        int ct = cntg[tok];
        if (ct == 0 || ct > 8) {
            if (slot == 0) {
                int pos = atomicAdd(wcnt2, 1);
                if (pos < 4096) wlist2[pos] = tok;
            }
            continue;
        }
        if (slot >= ct) continue;
        int code = listsg[tok * 8 + slot];
        paird[p] = faithful_d(z, emb, zsq[tok], esq[code], tok, code);
    }
}

// ---------------- pick: thread per hard token, lexicographic (d, code) argmin ----------------
__global__ __launch_bounds__(256) void vq_pick(const float* __restrict__ paird,
                                               const int* __restrict__ wcnt,
                                               const int* __restrict__ wlist,
                                               const int* __restrict__ cntg,
                                               const int* __restrict__ listsg,
                                               float* __restrict__ loss2,
                                               float* __restrict__ dout) {
    const int n = wcnt[0];
    for (int q = blockIdx.x * 256 + threadIdx.x; q < n; q += 256 * 256) {
        int tok = wlist[q];
        int ct = cntg[tok];
        if (ct == 0 || ct > 8) continue;   // scan kernel owns these
        float db = paird[q * 8];
        int cb = listsg[tok * 8];
        for (int i = 1; i < ct; ++i) {
            float d = paird[q * 8 + i];
            int c = listsg[tok * 8 + i];
            if (d < db || (d == db && c < cb)) { db = d; cb = c; }
        }
        dout[IDX_OFF + tok] = (float)cb;
        loss2[tok] = db;
    }
}

// ---------------- decide (scan): BLOCK per token, full 1024 faithful scan (rare) ----------------
__global__ __launch_bounds__(256) void vq_decide_scan(const float* __restrict__ z,
                                                      const float* __restrict__ emb,
                                                      const float* __restrict__ zsq,
                                                      const float* __restrict__ esq,
                                                      const int* __restrict__ wcnt2,
                                                      const int* __restrict__ wlist2,
                                                      float* __restrict__ loss2,
                                                      float* __restrict__ dout) {
    __shared__ __align__(16) float zrow[DIM];
    __shared__ float dred[256];
    __shared__ int   ired[256];
    int n = wcnt2[0];
    if (n > 4096) n = 4096;
    const int tid = threadIdx.x;
    for (int job = blockIdx.x; job < n; job += 64) {
        int tok = wlist2[job];
        __syncthreads();
        if (tid < 64) ((float4*)zrow)[tid] = ((const float4*)(z + (size_t)tok * DIM))[tid];
        __syncthreads();
        float zq = zsq[tok];
        float a0 = 0.f, a1v = 0.f, a2 = 0.f, a3 = 0.f;
        const float4* e0 = (const float4*)(emb + (size_t)(tid      ) * DIM);
        const float4* e1 = (const float4*)(emb + (size_t)(tid + 256) * DIM);
        const float4* e2 = (const float4*)(emb + (size_t)(tid + 512) * DIM);
        const float4* e3 = (const float4*)(emb + (size_t)(tid + 768) * DIM);
#pragma unroll
        for (int seg = 0; seg < 4; ++seg) {
            float4 zb[16];
#pragma unroll
            for (int qq = 0; qq < 16; ++qq) zb[qq] = ((float4*)zrow)[seg * 16 + qq];
#pragma unroll
            for (int qq = 0; qq < 16; ++qq) {
                float4 a = zb[qq];
                float4 b0 = e0[seg * 16 + qq], b1 = e1[seg * 16 + qq];
                float4 b2 = e2[seg * 16 + qq], b3 = e3[seg * 16 + qq];
                a0 = fmaf(a.x, b0.x, a0); a0 = fmaf(a.y, b0.y, a0);
                a0 = fmaf(a.z, b0.z, a0); a0 = fmaf(a.w, b0.w, a0);
                a1v = fmaf(a.x, b1.x, a1v); a1v = fmaf(a.y, b1.y, a1v);
                a1v = fmaf(a.z, b1.z, a1v); a1v = fmaf(a.w, b1.w, a1v);
                a2 = fmaf(a.x, b2.x, a2); a2 = fmaf(a.y, b2.y, a2);
                a2 = fmaf(a.z, b2.z, a2); a2 = fmaf(a.w, b2.w, a2);
                a3 = fmaf(a.x, b3.x, a3); a3 = fmaf(a.y, b3.y, a3);
                a3 = fmaf(a.z, b3.z, a3); a3 = fmaf(a.w, b3.w, a3);
            }
        }
        float d0 = (zq + esq[tid      ]) - 2.0f * a0;
        float d1 = (zq + esq[tid + 256]) - 2.0f * a1v;
        float d2 = (zq + esq[tid + 512]) - 2.0f * a2;
        float d3 = (zq + esq[tid + 768]) - 2.0f * a3;
        float db = d0; int cb = tid;
        if (d1 < db) { db = d1; cb = tid + 256; }
        if (d2 < db) { db = d2; cb = tid + 512; }
        if (d3 < db) { db = d3; cb = tid + 768; }
        dred[tid] = db; ired[tid] = cb;
        __syncthreads();
        for (int step = 128; step >= 1; step >>= 1) {
            if (tid < step) {
                float od = dred[tid + step]; int oi = ired[tid + step];
                if (od < dred[tid] || (od == dred[tid] && oi < ired[tid])) {
                    dred[tid] = od; ired[tid] = oi;
                }
            }
            __syncthreads();
        }
        if (tid == 0) {
            dout[IDX_OFF + tok] = (float)ired[0];
            loss2[tok] = dred[0];
        }
    }
}

// ---------------- loss reduction (fixed order) ----------------
__global__ __launch_bounds__(256) void vq_sum(const float* __restrict__ loss2,
                                              float* __restrict__ part) {
    __shared__ float ws[4];
    float s = 0.f;
#pragma unroll
    for (int q = 0; q < 4; ++q)
        s += loss2[blockIdx.x * 1024 + q * 256 + threadIdx.x];
#pragma unroll
    for (int m = 1; m < 64; m <<= 1) s += __shfl_xor(s, m, 64);
    if ((threadIdx.x & 63) == 0) ws[threadIdx.x >> 6] = s;
    __syncthreads();
    if (threadIdx.x == 0) part[blockIdx.x] = ws[0] + ws[1] + ws[2] + ws[3];
}

__global__ __launch_bounds__(64) void vq_final(const float* __restrict__ part,
                                               float* __restrict__ dout) {
    double s = (double)part[threadIdx.x];
#pragma unroll
    for (int m = 1; m < 64; m <<= 1) s += __shfl_xor(s, m, 64);
    if (threadIdx.x == 0) dout[LOSS_OFF] = (float)(s * 1.25 / 16777216.0);
}

// ---------------- gather z_q rows ----------------
__global__ __launch_bounds__(256) void vq_gather(const float* __restrict__ emb,
                                                 float* __restrict__ dout) {
    const int w = threadIdx.x >> 6, l = threadIdx.x & 63;
    for (int tok = blockIdx.x * 4 + w; tok < NTOK; tok += 2048 * 4) {
        int widx = (int)dout[IDX_OFF + tok];
        float4 ev = *(const float4*)&emb[(size_t)widx * DIM + l * 4];
        *(float4*)&dout[(size_t)tok * DIM + l * 4] = ev;
    }
}

extern "C" void kernel_launch(void* const* d_in, const int* in_sizes, int n_in,
                              void* d_out, int out_size, void* d_ws, size_t ws_size,
                              hipStream_t stream) {
    const float* z   = (const float*)d_in[0];
    const float* emb = (const float*)d_in[1];
    float* out = (float*)d_out;

    float* zsq   = out + SC_ZSQ;
    float* a1    = out + SC_A1;
    float* loss2 = out + SC_LOSS2;
    float* esq   = out + SC_ESQ;
    float* esqnh = out + SC_ESQNH;
    float* part  = out + SC_PART;
    int*   wcnt  = (int*)(out + SC_WCNT);
    int*   wcnt2 = (int*)(out + SC_WCNT2);
    int*   cntg  = (int*)(out + SC_CNTG);
    int*   listsg= (int*)(out + SC_LISTS);
    int*   wlist = (int*)(out + SC_WLIST);
    int*   wlist2= (int*)(out + SC_WLIST2);
    float* paird = out + SC_PAIRD;
    unsigned short* img  = (unsigned short*)(out + SC_EHIMG);
    unsigned short* zimg = (unsigned short*)(out + SC_ZIMG);

    vq_prep_esq <<<64,   256, 0, stream>>>(emb, esq, esqnh, wcnt, wcnt2);
    vq_prep_z   <<<4096, 256, 0, stream>>>(z, zsq, zimg);
    vq_prep_eimg<<<32,   256, 0, stream>>>(emb, img);
    vq_gemm<1>  <<<1024, 256, 0, stream>>>(zimg, img, esqnh, zsq, a1, wcnt, wlist, cntg, listsg, loss2, out);
    vq_gemm<2>  <<<1024, 256, 0, stream>>>(zimg, img, esqnh, zsq, a1, wcnt, wlist, cntg, listsg, loss2, out);
    vq_pairs    <<<2048, 256, 0, stream>>>(z, emb, zsq, esq, wcnt, wlist, cntg, listsg, wcnt2, wlist2, paird);
    vq_pick     <<<256,  256, 0, stream>>>(paird, wcnt, wlist, cntg, listsg, loss2, out);
    vq_decide_scan<<<64, 256, 0, stream>>>(z, emb, zsq, esq, wcnt2, wlist2, loss2, out);
    vq_sum      <<<64,   256, 0, stream>>>(loss2, part);
    vq_final    <<<1,    64,  0, stream>>>(part, out);
    vq_gather   <<<2048, 256, 0, stream>>>(emb, out);
}